// Round 11
// baseline (240.765 us; speedup 1.0000x reference)
//
#include <hip/hip_runtime.h>
#include <hip/hip_bf16.h>
#include <math.h>

#define N 8192
#define D 128
#define MARGIN_V 0.3f
#define NEG_FILL 1000000.0f

typedef short bf16x8 __attribute__((ext_vector_type(8)));
typedef float f32x4  __attribute__((ext_vector_type(4)));

// Fragment-major layout of Fb: frag (g,q) holds rows 16g..16g+15, k 32q..32q+31,
// stored as 64 lanes x 16B: lane L = row (L&15), k-subchunk (L>>4)*8..+7.
// Short index: ((g*4 + q)*64 + L)*8 + j. Serves both A and B operands.

// ---------- convert: F fp32 -> frag-major bf16, sq, init ap/an/counter ----------
__global__ __launch_bounds__(256) void convert_kernel(const float* __restrict__ F,
                                                      unsigned short* __restrict__ Fb,
                                                      float* __restrict__ sq,
                                                      unsigned* __restrict__ ap,
                                                      unsigned* __restrict__ an,
                                                      unsigned* __restrict__ counter) {
    __shared__ float red[16][17];
    const int g   = blockIdx.x;          // row group: 16 rows
    const int tid = threadIdx.x;
    const int q = tid >> 6, L = tid & 63;
    const int m = L & 15, j8 = (L >> 4) * 8;

    const float* src = F + (size_t)(16 * g + m) * D + 32 * q + j8;
    float4 v0 = *(const float4*)src;
    float4 v1 = *(const float4*)(src + 4);

    float s = v0.x * v0.x + v0.y * v0.y + v0.z * v0.z + v0.w * v0.w
            + v1.x * v1.x + v1.y * v1.y + v1.z * v1.z + v1.w * v1.w;

    union { bf16x8 v; __hip_bfloat162 h2[4]; } pk;
    pk.h2[0] = __float22bfloat162_rn({v0.x, v0.y});
    pk.h2[1] = __float22bfloat162_rn({v0.z, v0.w});
    pk.h2[2] = __float22bfloat162_rn({v1.x, v1.y});
    pk.h2[3] = __float22bfloat162_rn({v1.z, v1.w});
    *(bf16x8*)&Fb[(size_t)g * 2048 + tid * 8] = pk.v;   // coalesced 4 KB/block

    red[m][q * 4 + (L >> 4)] = s;
    __syncthreads();
    if (tid < 16) {
        float t = 0.f;
        #pragma unroll
        for (int c = 0; c < 16; ++c) t += red[tid][c];
        sq[16 * g + tid] = t;
    }
    int gid = blockIdx.x * 256 + tid;
    if (gid < N) { ap[gid] = 0u; an[gid] = 0x7F800000u; }   // 0.0f / +inf (d^2 domain)
    if (gid == 0) *counter = 0u;
}

// ---------- gemm: zero-LDS K-loop + last-block-done fused loss ----------
// Block = 4 waves x 32 rows (128-row strip) x 512-col chunk. Grid 64x16 = 1024.
// Mining is IDEMPOTENT (atomic min/max of pure functions of inputs), so the
// kernel can be launched twice; the completion counter reaches 1023 only in
// pass 1, so the fused loss fires exactly once per call.
__global__ __launch_bounds__(256, 4) void gemm_kernel(const unsigned short* __restrict__ Fb,
                                                      const float* __restrict__ sq,
                                                      const int* __restrict__ lab,
                                                      unsigned* __restrict__ ap,
                                                      unsigned* __restrict__ an,
                                                      unsigned* __restrict__ counter,
                                                      float* __restrict__ out) {
    const int tid  = threadIdx.x;
    const int wave = tid >> 6, lane = tid & 63;
    const int quad = lane >> 4, lr = lane & 15;
    const int R0   = blockIdx.x * 128 + wave * 32;  // this wave's 32 rows
    const int g0   = R0 >> 4;                       // 2 row-groups
    const int cg0  = blockIdx.y * 32;               // 32 col-groups in chunk
    const int colb = blockIdx.y * 512;

    // A fragments: 2 row-groups x 4 k-chunks, coalesced contiguous loads
    bf16x8 af[2][4];
    #pragma unroll
    for (int a = 0; a < 2; ++a)
        #pragma unroll
        for (int ks = 0; ks < 4; ++ks)
            af[a][ks] = *(const bf16x8*)&Fb[(((size_t)(g0 + a) * 4 + ks) * 64 + lane) * 8];

    int4 labi4[2];
    #pragma unroll
    for (int a = 0; a < 2; ++a)
        labi4[a] = *(const int4*)&lab[R0 + a * 16 + quad * 4];

    float rowP[2][4], rowN[2][4];
    #pragma unroll
    for (int a = 0; a < 2; ++a)
        #pragma unroll
        for (int r = 0; r < 4; ++r) { rowP[a][r] = -INFINITY; rowN[a][r] = INFINITY; }

    bf16x8 bf[2][4];
    float sqj[2], sqj_n[2];
    int   labj[2], labj_n[2];

    #pragma unroll
    for (int b = 0; b < 2; ++b) {
        int gb = cg0 + b;
        #pragma unroll
        for (int ks = 0; ks < 4; ++ks)
            bf[b][ks] = *(const bf16x8*)&Fb[(((size_t)gb * 4 + ks) * 64 + lane) * 8];
        sqj[b]  = sq[colb + b * 16 + lr];
        labj[b] = lab[colb + b * 16 + lr];
    }

    #pragma unroll 1
    for (int t = 0; t < 16; ++t) {
        f32x4 acc[2][2];
        #pragma unroll
        for (int a = 0; a < 2; ++a)
            #pragma unroll
            for (int b = 0; b < 2; ++b) acc[a][b] = {0.f, 0.f, 0.f, 0.f};
        #pragma unroll
        for (int ks = 0; ks < 4; ++ks)
            #pragma unroll
            for (int a = 0; a < 2; ++a)
                #pragma unroll
                for (int b = 0; b < 2; ++b)
                    acc[a][b] = __builtin_amdgcn_mfma_f32_16x16x32_bf16(
                        af[a][ks], bf[b][ks], acc[a][b], 0, 0, 0);

        if (t < 15) {
            #pragma unroll
            for (int b = 0; b < 2; ++b) {
                int gb = cg0 + 2 * (t + 1) + b;
                #pragma unroll
                for (int ks = 0; ks < 4; ++ks)
                    bf[b][ks] = *(const bf16x8*)&Fb[(((size_t)gb * 4 + ks) * 64 + lane) * 8];
                sqj_n[b]  = sq[colb + (t + 1) * 32 + b * 16 + lr];
                labj_n[b] = lab[colb + (t + 1) * 32 + b * 16 + lr];
            }
        }

        #pragma unroll
        for (int a = 0; a < 2; ++a)
            #pragma unroll
            for (int b = 0; b < 2; ++b)
                #pragma unroll
                for (int r = 0; r < 4; ++r) {
                    float u = fmaf(acc[a][b][r], -2.0f, sqj[b]);
                    bool same = (labi4[a][r] == labj[b]);
                    rowP[a][r] = fmaxf(rowP[a][r], same ? u : -INFINITY);
                    rowN[a][r] = fminf(rowN[a][r], same ? INFINITY : u);
                }
        #pragma unroll
        for (int b = 0; b < 2; ++b) { sqj[b] = sqj_n[b]; labj[b] = labj_n[b]; }
    }

    #pragma unroll
    for (int a = 0; a < 2; ++a)
        #pragma unroll
        for (int r = 0; r < 4; ++r) {
            float p = rowP[a][r], n = rowN[a][r];
            #pragma unroll
            for (int off = 1; off < 16; off <<= 1) {
                p = fmaxf(p, __shfl_xor(p, off));
                n = fminf(n, __shfl_xor(n, off));
            }
            rowP[a][r] = p; rowN[a][r] = n;
        }
    if (lr == 0) {
        #pragma unroll
        for (int a = 0; a < 2; ++a) {
            f32x4 sqi4 = *(const f32x4*)&sq[R0 + a * 16 + quad * 4];
            #pragma unroll
            for (int r = 0; r < 4; ++r) {
                int row = R0 + a * 16 + quad * 4 + r;
                float pd2 = fmaxf(sqi4[r] + rowP[a][r], 0.f);
                float nd2 = fmaxf(sqi4[r] + rowN[a][r], 0.f);
                atomicMax(&ap[row], __float_as_uint(pd2));
                atomicMin(&an[row], __float_as_uint(nd2));
            }
        }
    }

    // ---- last-block-done fused loss (fires only in pass 1: old == 1023) ----
    __shared__ unsigned done_old;
    __threadfence();
    __syncthreads();
    if (tid == 0) done_old = atomicAdd(counter, 1u);
    __syncthreads();
    if (done_old == gridDim.x * gridDim.y - 1) {
        __threadfence();
        float sum = 0.f;
        #pragma unroll
        for (int k = 0; k < 8; ++k) {
            int i = k * 1024 + tid * 4;
            f32x4 a4 = *(const f32x4*)&((const float*)ap)[i];
            f32x4 n4 = *(const f32x4*)&((const float*)an)[i];
            #pragma unroll
            for (int c = 0; c < 4; ++c) {
                float apd = __builtin_amdgcn_sqrtf(a4[c]);
                float anv = n4[c];
                float and_ = (anv < INFINITY) ? __builtin_amdgcn_sqrtf(anv) : NEG_FILL;
                sum += fmaxf(0.f, MARGIN_V - (and_ - apd));
            }
        }
        #pragma unroll
        for (int off = 32; off >= 1; off >>= 1) sum += __shfl_xor(sum, off);
        __shared__ float s4[4];
        if ((tid & 63) == 0) s4[tid >> 6] = sum;
        __syncthreads();
        if (tid == 0) out[0] = (s4[0] + s4[1] + s4[2] + s4[3]) * (1.0f / (float)N);
    }
}

extern "C" void kernel_launch(void* const* d_in, const int* in_sizes, int n_in,
                              void* d_out, int out_size, void* d_ws, size_t ws_size,
                              hipStream_t stream) {
    const float* F   = (const float*)d_in[0];
    const int*   lab = (const int*)d_in[1];

    unsigned short* Fb = (unsigned short*)d_ws;          // 2 MB, frag-major
    float*          sq = (float*)(Fb + (size_t)N * D);   // 32 KB
    unsigned*       ap = (unsigned*)(sq + N);            // 32 KB
    unsigned*       an = ap + N;                         // 32 KB
    unsigned*       counter = an + N;

    convert_kernel<<<N / 16, 256, 0, stream>>>(F, Fb, sq, ap, an, counter);
    // PROBE: launch the idempotent gemm twice; dur_us delta vs R10 reads out
    // gemm's true marginal cost. Loss fires only in pass 1 (counter==1023).
    gemm_kernel<<<dim3(64, 16), 256, 0, stream>>>(Fb, sq, lab, ap, an, counter, (float*)d_out);
    gemm_kernel<<<dim3(64, 16), 256, 0, stream>>>(Fb, sq, lab, ap, an, counter, (float*)d_out);
}

// Round 12
// 121.015 us; speedup vs baseline: 1.9895x; 1.9895x over previous
//
#include <hip/hip_runtime.h>
#include <hip/hip_bf16.h>
#include <math.h>

#define N 8192
#define D 128
#define MARGIN_V 0.3f
#define NEG_FILL 1000000.0f

typedef short bf16x8 __attribute__((ext_vector_type(8)));
typedef float f32x4  __attribute__((ext_vector_type(4)));

// Fragment-major layout of Fb: frag (g,q) holds rows 16g..16g+15, k 32q..32q+31,
// stored as 64 lanes x 16B: lane L = row (L&15), k-subchunk (L>>4)*8..+7.
// Short index: ((g*4 + q)*64 + L)*8 + j. Serves both A and B operands.
// cmeta[j] = { sq[j], bitcast(lab[j]) }.

// ---------- convert: F fp32 -> frag-major bf16, cmeta, init ap/an ----------
__global__ __launch_bounds__(256) void convert_kernel(const float* __restrict__ F,
                                                      const int* __restrict__ lab,
                                                      unsigned short* __restrict__ Fb,
                                                      float2* __restrict__ cmeta,
                                                      unsigned* __restrict__ ap,
                                                      unsigned* __restrict__ an) {
    __shared__ float red[16][17];
    const int g   = blockIdx.x;          // row group: 16 rows
    const int tid = threadIdx.x;
    const int q = tid >> 6, L = tid & 63;
    const int m = L & 15, j8 = (L >> 4) * 8;

    const float* src = F + (size_t)(16 * g + m) * D + 32 * q + j8;
    float4 v0 = *(const float4*)src;
    float4 v1 = *(const float4*)(src + 4);

    float s = v0.x * v0.x + v0.y * v0.y + v0.z * v0.z + v0.w * v0.w
            + v1.x * v1.x + v1.y * v1.y + v1.z * v1.z + v1.w * v1.w;

    union { bf16x8 v; __hip_bfloat162 h2[4]; } pk;
    pk.h2[0] = __float22bfloat162_rn({v0.x, v0.y});
    pk.h2[1] = __float22bfloat162_rn({v0.z, v0.w});
    pk.h2[2] = __float22bfloat162_rn({v1.x, v1.y});
    pk.h2[3] = __float22bfloat162_rn({v1.z, v1.w});
    *(bf16x8*)&Fb[(size_t)g * 2048 + tid * 8] = pk.v;   // coalesced 4 KB/block

    red[m][q * 4 + (L >> 4)] = s;
    __syncthreads();
    if (tid < 16) {
        float t = 0.f;
        #pragma unroll
        for (int c = 0; c < 16; ++c) t += red[tid][c];
        int row = 16 * g + tid;
        cmeta[row] = {t, __int_as_float(lab[row])};
    }
    int gid = blockIdx.x * 256 + tid;
    if (gid < N) { ap[gid] = 0u; an[gid] = 0x7F800000u; }   // 0.0f / +inf (d^2 domain)
}

// ---------- gemm: zero-LDS, zero-barrier, no VGPR clamp (spill-free) ----------
// Block = 4 waves x 32 rows (128-row strip) x 512-col chunk. Grid 64x16 = 1024.
// B frags single-buffered, next tile's loads issued after MFMA; mining in
// u = sqj - 2c domain in registers; sqrt deferred. Idempotent (atomic min/max),
// so it may be launched multiple times.
__global__ __launch_bounds__(256) void gemm_kernel(const unsigned short* __restrict__ Fb,
                                                   const float2* __restrict__ cmeta,
                                                   unsigned* __restrict__ ap,
                                                   unsigned* __restrict__ an) {
    const int tid  = threadIdx.x;
    const int wave = tid >> 6, lane = tid & 63;
    const int quad = lane >> 4, lr = lane & 15;
    const int R0   = blockIdx.x * 128 + wave * 32;  // this wave's 32 rows
    const int g0   = R0 >> 4;                       // 2 row-groups
    const int cg0  = blockIdx.y * 32;               // 32 col-groups in chunk
    const int colb = blockIdx.y * 512;

    // A fragments: 2 row-groups x 4 k-chunks, coalesced contiguous loads
    bf16x8 af[2][4];
    #pragma unroll
    for (int a = 0; a < 2; ++a)
        #pragma unroll
        for (int ks = 0; ks < 4; ++ks)
            af[a][ks] = *(const bf16x8*)&Fb[(((size_t)(g0 + a) * 4 + ks) * 64 + lane) * 8];

    int labi[2][4];
    #pragma unroll
    for (int a = 0; a < 2; ++a)
        #pragma unroll
        for (int r = 0; r < 4; ++r)
            labi[a][r] = __float_as_int(cmeta[R0 + a * 16 + quad * 4 + r].y);

    float rowP[2][4], rowN[2][4];
    #pragma unroll
    for (int a = 0; a < 2; ++a)
        #pragma unroll
        for (int r = 0; r < 4; ++r) { rowP[a][r] = -INFINITY; rowN[a][r] = INFINITY; }

    bf16x8 bf[2][4];
    float sqj[2], sqj_n[2];
    int   labj[2], labj_n[2];

    #pragma unroll
    for (int b = 0; b < 2; ++b) {
        int gb = cg0 + b;
        #pragma unroll
        for (int ks = 0; ks < 4; ++ks)
            bf[b][ks] = *(const bf16x8*)&Fb[(((size_t)gb * 4 + ks) * 64 + lane) * 8];
        float2 mt = cmeta[colb + b * 16 + lr];
        sqj[b] = mt.x; labj[b] = __float_as_int(mt.y);
    }

    #pragma unroll 1
    for (int t = 0; t < 16; ++t) {
        f32x4 acc[2][2];
        #pragma unroll
        for (int a = 0; a < 2; ++a)
            #pragma unroll
            for (int b = 0; b < 2; ++b) acc[a][b] = {0.f, 0.f, 0.f, 0.f};
        #pragma unroll
        for (int ks = 0; ks < 4; ++ks)
            #pragma unroll
            for (int a = 0; a < 2; ++a)
                #pragma unroll
                for (int b = 0; b < 2; ++b)
                    acc[a][b] = __builtin_amdgcn_mfma_f32_16x16x32_bf16(
                        af[a][ks], bf[b][ks], acc[a][b], 0, 0, 0);

        // prefetch tile t+1 (B frags + packed metadata)
        if (t < 15) {
            #pragma unroll
            for (int b = 0; b < 2; ++b) {
                int gb = cg0 + 2 * (t + 1) + b;
                #pragma unroll
                for (int ks = 0; ks < 4; ++ks)
                    bf[b][ks] = *(const bf16x8*)&Fb[(((size_t)gb * 4 + ks) * 64 + lane) * 8];
                float2 mt = cmeta[colb + (t + 1) * 32 + b * 16 + lr];
                sqj_n[b] = mt.x; labj_n[b] = __float_as_int(mt.y);
            }
        }

        // epilogue on current acc (overlaps in-flight loads)
        #pragma unroll
        for (int a = 0; a < 2; ++a)
            #pragma unroll
            for (int b = 0; b < 2; ++b)
                #pragma unroll
                for (int r = 0; r < 4; ++r) {
                    float u = fmaf(acc[a][b][r], -2.0f, sqj[b]);
                    bool same = (labi[a][r] == labj[b]);
                    rowP[a][r] = fmaxf(rowP[a][r], same ? u : -INFINITY);
                    rowN[a][r] = fminf(rowN[a][r], same ? INFINITY : u);
                }
        #pragma unroll
        for (int b = 0; b < 2; ++b) { sqj[b] = sqj_n[b]; labj[b] = labj_n[b]; }
    }

    // reduce over the 16 lr lanes, reload sqi, clamp, atomic d^2-bit combine
    #pragma unroll
    for (int a = 0; a < 2; ++a)
        #pragma unroll
        for (int r = 0; r < 4; ++r) {
            float p = rowP[a][r], n = rowN[a][r];
            #pragma unroll
            for (int off = 1; off < 16; off <<= 1) {
                p = fmaxf(p, __shfl_xor(p, off));
                n = fminf(n, __shfl_xor(n, off));
            }
            rowP[a][r] = p; rowN[a][r] = n;
        }
    if (lr == 0) {
        #pragma unroll
        for (int a = 0; a < 2; ++a)
            #pragma unroll
            for (int r = 0; r < 4; ++r) {
                int row = R0 + a * 16 + quad * 4 + r;
                float sqi = cmeta[row].x;
                float pd2 = fmaxf(sqi + rowP[a][r], 0.f);   // -inf -> 0 (no-op vs init)
                float nd2 = fmaxf(sqi + rowN[a][r], 0.f);   // +inf stays +inf (no-op)
                atomicMax(&ap[row], __float_as_uint(pd2));
                atomicMin(&an[row], __float_as_uint(nd2));
            }
    }
}

// ---------- loss: single block, reads d^2, sqrt here, writes out[0] ----------
__global__ __launch_bounds__(256) void loss_kernel(const float* __restrict__ ap,
                                                   const float* __restrict__ an,
                                                   float* __restrict__ out) {
    int tid = threadIdx.x;
    float sum = 0.f;
    #pragma unroll
    for (int k = 0; k < 8; ++k) {
        int i = k * 1024 + tid * 4;
        f32x4 a4 = *(const f32x4*)&ap[i];
        f32x4 n4 = *(const f32x4*)&an[i];
        #pragma unroll
        for (int c = 0; c < 4; ++c) {
            float apd = __builtin_amdgcn_sqrtf(a4[c]);
            float anv = n4[c];
            float and_ = (anv < INFINITY) ? __builtin_amdgcn_sqrtf(anv) : NEG_FILL;
            sum += fmaxf(0.f, MARGIN_V - (and_ - apd));
        }
    }
    #pragma unroll
    for (int off = 32; off >= 1; off >>= 1) sum += __shfl_xor(sum, off);
    __shared__ float s4[4];
    if ((tid & 63) == 0) s4[tid >> 6] = sum;
    __syncthreads();
    if (tid == 0) out[0] = (s4[0] + s4[1] + s4[2] + s4[3]) * (1.0f / (float)N);
}

extern "C" void kernel_launch(void* const* d_in, const int* in_sizes, int n_in,
                              void* d_out, int out_size, void* d_ws, size_t ws_size,
                              hipStream_t stream) {
    const float* F   = (const float*)d_in[0];
    const int*   lab = (const int*)d_in[1];

    unsigned short* Fb    = (unsigned short*)d_ws;           // 2 MB, frag-major
    float2*         cmeta = (float2*)(Fb + (size_t)N * D);   // 64 KB
    unsigned*       ap    = (unsigned*)(cmeta + N);          // 32 KB
    unsigned*       an    = ap + N;                          // 32 KB

    convert_kernel<<<N / 16, 256, 0, stream>>>(F, lab, Fb, cmeta, ap, an);
    // PROBE: idempotent gemm launched twice; dur_us delta vs single-launch
    // baseline reads out gemm's true marginal cost (spill-free this time).
    gemm_kernel<<<dim3(64, 16), 256, 0, stream>>>(Fb, cmeta, ap, an);
    gemm_kernel<<<dim3(64, 16), 256, 0, stream>>>(Fb, cmeta, ap, an);
    loss_kernel<<<1, 256, 0, stream>>>((const float*)ap, (const float*)an, (float*)d_out);
}

// Round 13
// 86.145 us; speedup vs baseline: 2.7949x; 1.4048x over previous
//
#include <hip/hip_runtime.h>
#include <hip/hip_bf16.h>
#include <math.h>

#define N 8192
#define D 128
#define MARGIN_V 0.3f
#define NEG_FILL 1000000.0f

typedef short bf16x8 __attribute__((ext_vector_type(8)));
typedef float f32x4  __attribute__((ext_vector_type(4)));

// Fragment-major layout of Fb: frag (g,q) holds rows 16g..16g+15, k 32q..32q+31,
// stored as 64 lanes x 16B: lane L = row (L&15), k-subchunk (L>>4)*8..+7.
// Short index: ((g*4 + q)*64 + L)*8 + j. Serves both A and B operands.
// cmeta[j] = { sq[j], bitcast(lab[j]) }.

// ---------- convert: F fp32 -> frag-major bf16, cmeta, init ap/an ----------
__global__ __launch_bounds__(256) void convert_kernel(const float* __restrict__ F,
                                                      const int* __restrict__ lab,
                                                      unsigned short* __restrict__ Fb,
                                                      float2* __restrict__ cmeta,
                                                      unsigned* __restrict__ ap,
                                                      unsigned* __restrict__ an) {
    __shared__ float red[16][17];
    const int g   = blockIdx.x;          // row group: 16 rows
    const int tid = threadIdx.x;
    const int q = tid >> 6, L = tid & 63;
    const int m = L & 15, j8 = (L >> 4) * 8;

    const float* src = F + (size_t)(16 * g + m) * D + 32 * q + j8;
    float4 v0 = *(const float4*)src;
    float4 v1 = *(const float4*)(src + 4);

    float s = v0.x * v0.x + v0.y * v0.y + v0.z * v0.z + v0.w * v0.w
            + v1.x * v1.x + v1.y * v1.y + v1.z * v1.z + v1.w * v1.w;

    union { bf16x8 v; __hip_bfloat162 h2[4]; } pk;
    pk.h2[0] = __float22bfloat162_rn({v0.x, v0.y});
    pk.h2[1] = __float22bfloat162_rn({v0.z, v0.w});
    pk.h2[2] = __float22bfloat162_rn({v1.x, v1.y});
    pk.h2[3] = __float22bfloat162_rn({v1.z, v1.w});
    *(bf16x8*)&Fb[(size_t)g * 2048 + tid * 8] = pk.v;   // coalesced 4 KB/block

    red[m][q * 4 + (L >> 4)] = s;
    __syncthreads();
    if (tid < 16) {
        float t = 0.f;
        #pragma unroll
        for (int c = 0; c < 16; ++c) t += red[tid][c];
        int row = 16 * g + tid;
        cmeta[row] = {t, __int_as_float(lab[row])};
    }
    int gid = blockIdx.x * 256 + tid;
    if (gid < N) { ap[gid] = 0u; an[gid] = 0x7F800000u; }   // 0.0f / +inf (d^2 domain)
}

// ---------- gemm: zero-LDS K-loop, TRIANGLE blocks, dual row+col mining ----------
// Block = (strip s: 128 rows, 32/wave) x (chunk c: 512 cols), only c >= s/4:
// 544 blocks; per-block tiles t0..15 with t0 = max(0, 4s-16c) -> 50.8% of the
// full-matrix tiles. Rows mined in registers (u = sqj-2c domain); cols mined in
// d^2 domain into per-wave LDS slots (no loop barriers), merged once at the end.
// Coverage: (i->j, j>=i) row-mined at (s=i/128, c=j/512); (i->j, j<i) col-mined
// at (s=j/128, c=i/512). Duplicates harmless (idempotent min/max atomics).
__global__ __launch_bounds__(256) void gemm_kernel(const unsigned short* __restrict__ Fb,
                                                   const float2* __restrict__ cmeta,
                                                   unsigned* __restrict__ ap,
                                                   unsigned* __restrict__ an) {
    __shared__ float colAP[4][512];   // per-wave col accumulators (d^2 domain)
    __shared__ float colAN[4][512];

    // decode blockIdx -> (s, c)
    int k = blockIdx.x;
    int s = 0, cum = 0;
    while (true) { int cnt = 16 - (s >> 2); if (k < cum + cnt) break; cum += cnt; ++s; }
    int c = (s >> 2) + (k - cum);
    int t0 = 4 * s - 16 * c; if (t0 < 0) t0 = 0;

    const int tid  = threadIdx.x;
    const int wave = tid >> 6, lane = tid & 63;
    const int quad = lane >> 4, lr = lane & 15;
    const int R0   = s * 128 + wave * 32;   // this wave's 32 rows
    const int g0   = R0 >> 4;               // 2 row-groups
    const int cg0  = c * 32;                // 32 col-groups in chunk
    const int colb = c * 512;

    // init this wave's col slots (identity)
    #pragma unroll
    for (int ii = 0; ii < 2; ++ii) {
        *(f32x4*)&colAP[wave][lane * 8 + ii * 4] = {-INFINITY, -INFINITY, -INFINITY, -INFINITY};
        *(f32x4*)&colAN[wave][lane * 8 + ii * 4] = { INFINITY,  INFINITY,  INFINITY,  INFINITY};
    }

    // A fragments: 2 row-groups x 4 k-chunks, coalesced contiguous loads
    bf16x8 af[2][4];
    #pragma unroll
    for (int a = 0; a < 2; ++a)
        #pragma unroll
        for (int ks = 0; ks < 4; ++ks)
            af[a][ks] = *(const bf16x8*)&Fb[(((size_t)(g0 + a) * 4 + ks) * 64 + lane) * 8];

    float sqi[2][4]; int labi[2][4];
    #pragma unroll
    for (int a = 0; a < 2; ++a)
        #pragma unroll
        for (int r = 0; r < 4; ++r) {
            float2 mt = cmeta[R0 + a * 16 + quad * 4 + r];
            sqi[a][r] = mt.x; labi[a][r] = __float_as_int(mt.y);
        }

    float rowP[2][4], rowN[2][4];
    #pragma unroll
    for (int a = 0; a < 2; ++a)
        #pragma unroll
        for (int r = 0; r < 4; ++r) { rowP[a][r] = -INFINITY; rowN[a][r] = INFINITY; }

    bf16x8 bf[2][4];
    float sqj[2], sqj_n[2];
    int   labj[2], labj_n[2];

    // load first tile t0
    #pragma unroll
    for (int b = 0; b < 2; ++b) {
        int gb = cg0 + 2 * t0 + b;
        #pragma unroll
        for (int ks = 0; ks < 4; ++ks)
            bf[b][ks] = *(const bf16x8*)&Fb[(((size_t)gb * 4 + ks) * 64 + lane) * 8];
        float2 mt = cmeta[colb + t0 * 32 + b * 16 + lr];
        sqj[b] = mt.x; labj[b] = __float_as_int(mt.y);
    }

    #pragma unroll 1
    for (int t = t0; t < 16; ++t) {
        f32x4 acc[2][2];
        #pragma unroll
        for (int a = 0; a < 2; ++a)
            #pragma unroll
            for (int b = 0; b < 2; ++b) acc[a][b] = {0.f, 0.f, 0.f, 0.f};
        #pragma unroll
        for (int ks = 0; ks < 4; ++ks)
            #pragma unroll
            for (int a = 0; a < 2; ++a)
                #pragma unroll
                for (int b = 0; b < 2; ++b)
                    acc[a][b] = __builtin_amdgcn_mfma_f32_16x16x32_bf16(
                        af[a][ks], bf[b][ks], acc[a][b], 0, 0, 0);

        // prefetch tile t+1 (B frags + packed metadata)
        if (t < 15) {
            #pragma unroll
            for (int b = 0; b < 2; ++b) {
                int gb = cg0 + 2 * (t + 1) + b;
                #pragma unroll
                for (int ks = 0; ks < 4; ++ks)
                    bf[b][ks] = *(const bf16x8*)&Fb[(((size_t)gb * 4 + ks) * 64 + lane) * 8];
                float2 mt = cmeta[colb + (t + 1) * 32 + b * 16 + lr];
                sqj_n[b] = mt.x; labj_n[b] = __float_as_int(mt.y);
            }
        }

        // dual-mining epilogue (overlaps in-flight loads)
        float colP[2] = {-INFINITY, -INFINITY}, colN[2] = {INFINITY, INFINITY};
        #pragma unroll
        for (int a = 0; a < 2; ++a)
            #pragma unroll
            for (int b = 0; b < 2; ++b)
                #pragma unroll
                for (int r = 0; r < 4; ++r) {
                    float u  = fmaf(acc[a][b][r], -2.0f, sqj[b]);
                    float d2 = u + sqi[a][r];
                    bool same = (labi[a][r] == labj[b]);
                    rowP[a][r] = fmaxf(rowP[a][r], same ? u : -INFINITY);
                    rowN[a][r] = fminf(rowN[a][r], same ? INFINITY : u);
                    colP[b] = fmaxf(colP[b], same ? d2 : -INFINITY);
                    colN[b] = fminf(colN[b], same ? INFINITY : d2);
                }
        // col partials: reduce across quads, store to this wave's LDS slot
        #pragma unroll
        for (int b = 0; b < 2; ++b) {
            colP[b] = fmaxf(colP[b], __shfl_xor(colP[b], 16));
            colP[b] = fmaxf(colP[b], __shfl_xor(colP[b], 32));
            colN[b] = fminf(colN[b], __shfl_xor(colN[b], 16));
            colN[b] = fminf(colN[b], __shfl_xor(colN[b], 32));
        }
        if (quad == 0) {
            #pragma unroll
            for (int b = 0; b < 2; ++b) {
                int col = t * 32 + b * 16 + lr;
                colAP[wave][col] = colP[b];
                colAN[wave][col] = colN[b];
            }
        }
        #pragma unroll
        for (int b = 0; b < 2; ++b) { sqj[b] = sqj_n[b]; labj[b] = labj_n[b]; }
    }

    // row write-out: reduce over 16 lr lanes, add sqi, clamp, atomic combine
    #pragma unroll
    for (int a = 0; a < 2; ++a)
        #pragma unroll
        for (int r = 0; r < 4; ++r) {
            float p = rowP[a][r], n = rowN[a][r];
            #pragma unroll
            for (int off = 1; off < 16; off <<= 1) {
                p = fmaxf(p, __shfl_xor(p, off));
                n = fminf(n, __shfl_xor(n, off));
            }
            rowP[a][r] = p; rowN[a][r] = n;
        }
    if (lr == 0) {
        #pragma unroll
        for (int a = 0; a < 2; ++a)
            #pragma unroll
            for (int r = 0; r < 4; ++r) {
                int row = R0 + a * 16 + quad * 4 + r;
                float pd2 = fmaxf(sqi[a][r] + rowP[a][r], 0.f);   // -inf -> 0 (no-op)
                float nd2 = fmaxf(sqi[a][r] + rowN[a][r], 0.f);   // +inf stays (no-op)
                atomicMax(&ap[row], __float_as_uint(pd2));
                atomicMin(&an[row], __float_as_uint(nd2));
            }
    }

    // col write-out: merge the 4 wave slots, clamp, atomic combine
    __syncthreads();
    #pragma unroll
    for (int jj = tid; jj < 512; jj += 256) {
        float P = fmaxf(fmaxf(colAP[0][jj], colAP[1][jj]), fmaxf(colAP[2][jj], colAP[3][jj]));
        float Nv = fminf(fminf(colAN[0][jj], colAN[1][jj]), fminf(colAN[2][jj], colAN[3][jj]));
        atomicMax(&ap[colb + jj], __float_as_uint(fmaxf(P, 0.f)));   // -inf -> 0: no-op
        atomicMin(&an[colb + jj], __float_as_uint(fmaxf(Nv, 0.f)));  // +inf: no-op
    }
}

// ---------- loss: single block, reads d^2, sqrt here, writes out[0] ----------
__global__ __launch_bounds__(256) void loss_kernel(const float* __restrict__ ap,
                                                   const float* __restrict__ an,
                                                   float* __restrict__ out) {
    int tid = threadIdx.x;
    float sum = 0.f;
    #pragma unroll
    for (int k = 0; k < 8; ++k) {
        int i = k * 1024 + tid * 4;
        f32x4 a4 = *(const f32x4*)&ap[i];
        f32x4 n4 = *(const f32x4*)&an[i];
        #pragma unroll
        for (int c = 0; c < 4; ++c) {
            float apd = __builtin_amdgcn_sqrtf(a4[c]);
            float anv = n4[c];
            float and_ = (anv < INFINITY) ? __builtin_amdgcn_sqrtf(anv) : NEG_FILL;
            sum += fmaxf(0.f, MARGIN_V - (and_ - apd));
        }
    }
    #pragma unroll
    for (int off = 32; off >= 1; off >>= 1) sum += __shfl_xor(sum, off);
    __shared__ float s4[4];
    if ((tid & 63) == 0) s4[tid >> 6] = sum;
    __syncthreads();
    if (tid == 0) out[0] = (s4[0] + s4[1] + s4[2] + s4[3]) * (1.0f / (float)N);
}

extern "C" void kernel_launch(void* const* d_in, const int* in_sizes, int n_in,
                              void* d_out, int out_size, void* d_ws, size_t ws_size,
                              hipStream_t stream) {
    const float* F   = (const float*)d_in[0];
    const int*   lab = (const int*)d_in[1];

    unsigned short* Fb    = (unsigned short*)d_ws;           // 2 MB, frag-major
    float2*         cmeta = (float2*)(Fb + (size_t)N * D);   // 64 KB
    unsigned*       ap    = (unsigned*)(cmeta + N);          // 32 KB
    unsigned*       an    = ap + N;                          // 32 KB

    convert_kernel<<<N / 16, 256, 0, stream>>>(F, lab, Fb, cmeta, ap, an);
    gemm_kernel<<<544, 256, 0, stream>>>(Fb, cmeta, ap, an);
    loss_kernel<<<1, 256, 0, stream>>>((const float*)ap, (const float*)an, (float*)d_out);
}